// Round 4
// baseline (263.337 us; speedup 1.0000x reference)
//
#include <hip/hip_runtime.h>
#include <math.h>

namespace {
constexpr int kB = 4096, kN = 128, kT = 20, kD = 64, kP = 8;
// f32(2*pi) = 6.2831855f ; f32(2*pi/8) = 0.78539816f (exactly 1/8 of the former)
constexpr float kTwoPi = 6.28318530717958647692f;
constexpr float kBinW  = 0.78539816339744830962f;
}

__global__ __launch_bounds__(256)
void circle_kernel(const float* __restrict__ ego,
                   const float* __restrict__ nei,
                   const float* __restrict__ fres,
                   const float* __restrict__ Wce,
                   const float* __restrict__ bce,
                   float* __restrict__ out) {
  const int b   = blockIdx.x;
  const int tid = threadIdx.x;
  const int lane = tid & 63;
  const int wv   = tid >> 6;

  __shared__ float  s_nsum[kN];
  __shared__ float  s_lastx[kN], s_lasty[kN];
  __shared__ int    s_bin[kN];
  __shared__ float  s_cnt[kP], s_sdist[kP], s_sdir[kP];
  __shared__ float4 s_res[4][kP][kD / 4];   // per-wave partials, 8 KB

  if (tid < kN) s_nsum[tid] = 0.0f;
  if (tid < kP) { s_cnt[tid] = 0.0f; s_sdist[tid] = 0.0f; s_sdir[tid] = 0.0f; }
  __syncthreads();

  // ---- phase 1: full-trajectory sums (validity mask) + last-frame positions.
  // nei[b] = 128 neighbors x 40 floats = 1280 float4, perfectly coalesced.
  const float4* nb4 = reinterpret_cast<const float4*>(nei + (size_t)b * (kN * kT * 2));
  #pragma unroll
  for (int i = 0; i < 5; ++i) {
    const int j = tid + 256 * i;           // 0..1279
    const float4 v = nb4[j];
    const int n = j / 10;                  // 10 float4 per neighbor (40 % 4 == 0)
    atomicAdd(&s_nsum[n], (v.x + v.y) + (v.z + v.w));
    if (j - n * 10 == 9) { s_lastx[n] = v.z; s_lasty[n] = v.w; }  // floats 38,39
  }
  const float egx = ego[(size_t)b * (kT * 2) + (kT - 1) * 2 + 0];
  const float egy = ego[(size_t)b * (kT * 2) + (kT - 1) * 2 + 1];
  __syncthreads();

  // ---- phase 2: per-neighbor distance / direction / bin index
  if (tid < kN) {
    const float rx = s_lastx[tid] - egx;
    const float ry = s_lasty[tid] - egy;
    const float dist = sqrtf(rx * rx + ry * ry);
    // correctly-rounded f32 atan2 via double, to bit-match numpy's arctan2
    float dir = (float)atan2((double)rx, (double)ry);
    if (dir < 0.0f) dir += kTwoPi;         // == np.mod(dir, 2pi) for |dir| <= pi
    int idx = (int)(dir / kBinW);          // trunc, matches astype(int32)
    if (s_nsum[tid] == 0.0f) idx = -1;     // invalid neighbor -> -1
    s_bin[tid] = idx;                      // idx==8 possible (dir rounds to 2pi_f)
    if (idx >= 0 && idx < kP) {            // reference one-hot drops idx==8 and -1
      atomicAdd(&s_cnt[idx],  1.0f);
      atomicAdd(&s_sdist[idx], dist);
      atomicAdd(&s_sdir[idx],  dir);
    }
  }
  __syncthreads();

  // ---- phase 3: resonance scatter-reduce (dominant read: 32 KB/block)
  const float4* r4 = reinterpret_cast<const float4*>(fres + (size_t)b * (kN * kD));
  const int rsub = lane >> 4;              // which of 4 rows this lane covers
  const int dq   = lane & 15;              // float4 index within a row (d = 4*dq)
  float acc[kP][4];
  #pragma unroll
  for (int p = 0; p < kP; ++p) { acc[p][0] = acc[p][1] = acc[p][2] = acc[p][3] = 0.0f; }
  #pragma unroll
  for (int k = 0; k < 8; ++k) {
    const int n = wv * 32 + k * 4 + rsub;  // wave covers 32 rows, 4 per iter
    const float4 v = r4[n * 16 + dq];      // 1 KB contiguous per wave instr
    const int bin = s_bin[n];
    #pragma unroll
    for (int p = 0; p < kP; ++p) {
      const float mf = (bin == p) ? 1.0f : 0.0f;
      acc[p][0] = fmaf(v.x, mf, acc[p][0]);
      acc[p][1] = fmaf(v.y, mf, acc[p][1]);
      acc[p][2] = fmaf(v.z, mf, acc[p][2]);
      acc[p][3] = fmaf(v.w, mf, acc[p][3]);
    }
  }
  // reduce the 4 row-subgroups (lanes stride 16) within the wave
  #pragma unroll
  for (int p = 0; p < kP; ++p) {
    #pragma unroll
    for (int j = 0; j < 4; ++j) {
      float x = acc[p][j];
      x += __shfl_xor(x, 16, 64);
      x += __shfl_xor(x, 32, 64);
      acc[p][j] = x;
    }
  }
  if (lane < 16) {
    #pragma unroll
    for (int p = 0; p < kP; ++p)
      s_res[wv][p][dq] = make_float4(acc[p][0], acc[p][1], acc[p][2], acc[p][3]);
  }
  __syncthreads();

  // ---- epilogue: 256 float4 = 1024 floats per b, fully coalesced stores
  const int p = tid >> 5;                  // 8 partitions x 32 float4 each
  const int q = tid & 31;
  const float nf = s_cnt[p] + 1e-4f;
  float* ob = out + (size_t)b * (kP * 2 * kD) + p * (2 * kD);
  if (q < 16) {                            // resonance_circle half
    const float4 a = s_res[0][p][q], c = s_res[1][p][q];
    const float4 d2 = s_res[2][p][q], e = s_res[3][p][q];
    float4 o;
    o.x = (a.x + c.x + d2.x + e.x) / nf;
    o.y = (a.y + c.y + d2.y + e.y) / nf;
    o.z = (a.z + c.z + d2.z + e.z) / nf;
    o.w = (a.w + c.w + d2.w + e.w) / nf;
    reinterpret_cast<float4*>(ob)[q] = o;
  } else {                                 // f_scan half: relu(s0*W0 + s1*W1 + b)
    const int d = (q - 16) * 4;
    const float s0 = s_sdist[p] / nf;
    const float s1 = s_sdir[p] / nf;
    float4 o;
    o.x = fmaxf(s0 * Wce[d + 0] + s1 * Wce[kD + d + 0] + bce[d + 0], 0.0f);
    o.y = fmaxf(s0 * Wce[d + 1] + s1 * Wce[kD + d + 1] + bce[d + 1], 0.0f);
    o.z = fmaxf(s0 * Wce[d + 2] + s1 * Wce[kD + d + 2] + bce[d + 2], 0.0f);
    o.w = fmaxf(s0 * Wce[d + 3] + s1 * Wce[kD + d + 3] + bce[d + 3], 0.0f);
    reinterpret_cast<float4*>(ob + kD)[q - 16] = o;
  }
}

extern "C" void kernel_launch(void* const* d_in, const int* in_sizes, int n_in,
                              void* d_out, int out_size, void* d_ws, size_t ws_size,
                              hipStream_t stream) {
  const float* ego  = (const float*)d_in[0];
  const float* nei  = (const float*)d_in[1];
  const float* fres = (const float*)d_in[2];
  const float* Wce  = (const float*)d_in[3];
  const float* bce  = (const float*)d_in[4];
  float* out = (float*)d_out;
  hipLaunchKernelGGL(circle_kernel, dim3(kB), dim3(256), 0, stream,
                     ego, nei, fres, Wce, bce, out);
}

// Round 5
// 257.833 us; speedup vs baseline: 1.0213x; 1.0213x over previous
//
#include <hip/hip_runtime.h>
#include <math.h>

namespace {
constexpr int kB = 4096, kN = 128, kT = 20, kD = 64, kP = 8;
constexpr float kTwoPi = 6.28318530717958647692f;
constexpr float kBinW  = 0.78539816339744830962f;  // 2pi/8 in f32
}

// ---------------- K1: per-neighbor bin + per-(b,p) scan sums ----------------
// 2 threads per neighbor; each reads 20 contiguous floats (5x float4, 80 B).
// No LDS atomics for the validity sum: pair-combine via shfl. Only 8-wide
// LDS atomics for the scan sums (128 lanes -> 8 addrs, negligible).
__global__ __launch_bounds__(256)
void bin_kernel(const float* __restrict__ ego,
                const float* __restrict__ nei,
                int*   __restrict__ wbin,
                float* __restrict__ wcnt,
                float* __restrict__ wdist,
                float* __restrict__ wdir) {
  const int b = blockIdx.x, tid = threadIdx.x;
  const int n = tid >> 1, h = tid & 1;          // neighbor, half
  __shared__ float s_cnt[kP], s_d[kP], s_th[kP];
  if (tid < kP) { s_cnt[tid] = 0.f; s_d[tid] = 0.f; s_th[tid] = 0.f; }
  __syncthreads();

  const float4* p4 = reinterpret_cast<const float4*>(
      nei + (size_t)b * (kN * kT * 2) + n * 40 + h * 20);
  const float4 v0 = p4[0], v1 = p4[1], v2 = p4[2], v3 = p4[3], v4 = p4[4];
  float s = ((v0.x + v0.y) + (v0.z + v0.w)) + ((v1.x + v1.y) + (v1.z + v1.w))
          + ((v2.x + v2.y) + (v2.z + v2.w)) + ((v3.x + v3.y) + (v3.z + v3.w))
          + ((v4.x + v4.y) + (v4.z + v4.w));
  const float tot = s + __shfl_xor(s, 1, 64);   // pair (2n, 2n+1) same wave
  const float lx = __shfl_xor(v4.z, 1, 64);     // odd lane's floats 38,39 =
  const float ly = __shfl_xor(v4.w, 1, 64);     // last-frame x,y -> even lane

  if (h == 0) {
    const float egx = ego[(size_t)b * (kT * 2) + 38];
    const float egy = ego[(size_t)b * (kT * 2) + 39];
    const float rx = lx - egx, ry = ly - egy;
    const float dist = sqrtf(rx * rx + ry * ry);
    // correctly-rounded f32 atan2 via double (bit-matches numpy; proven R4)
    float dir = (float)atan2((double)rx, (double)ry);
    if (dir < 0.0f) dir += kTwoPi;
    int idx = (int)(dir / kBinW);               // trunc, matches astype(int32)
    if (tot == 0.0f) idx = -1;                  // invalid neighbor
    wbin[(size_t)b * kN + n] = idx;             // idx==8 possible; dropped later
    if (idx >= 0 && idx < kP) {
      atomicAdd(&s_cnt[idx], 1.0f);
      atomicAdd(&s_d[idx],  dist);
      atomicAdd(&s_th[idx], dir);
    }
  }
  __syncthreads();
  if (tid < kP) {
    wcnt [b * kP + tid] = s_cnt[tid];
    wdist[b * kP + tid] = s_d[tid];
    wdir [b * kP + tid] = s_th[tid];
  }
}

// ---------------- K2: barrier-free resonance stream + epilogue ----------------
__global__ __launch_bounds__(256)
void gather_kernel(const float* __restrict__ fres,
                   const int*   __restrict__ wbin,
                   const float* __restrict__ wcnt,
                   const float* __restrict__ wdist,
                   const float* __restrict__ wdir,
                   const float* __restrict__ Wce,
                   const float* __restrict__ bce,
                   float* __restrict__ out) {
  const int b = blockIdx.x, tid = threadIdx.x;
  const int lane = tid & 63, wv = tid >> 6;
  const int rsub = lane >> 4;                   // row subgroup (4 rows/iter)
  const int dq   = lane & 15;                   // float4 index within row
  __shared__ float4 s_res[4][kP][kD / 4];       // 8 KB partials

  const float4* r4 = reinterpret_cast<const float4*>(fres + (size_t)b * (kN * kD));
  const int* bb = wbin + (size_t)b * kN;        // L2-hot, 512 B

  float acc[kP][4];
  #pragma unroll
  for (int p = 0; p < kP; ++p) { acc[p][0] = acc[p][1] = acc[p][2] = acc[p][3] = 0.f; }

  // 8 independent float4 loads + 8 tiny bin loads; no barrier anywhere here.
  #pragma unroll
  for (int k = 0; k < 8; ++k) {
    const int n = wv * 32 + k * 4 + rsub;
    const float4 v = r4[n * 16 + dq];           // wave reads 1 KB contiguous
    const int bin = bb[n];
    #pragma unroll
    for (int p = 0; p < kP; ++p) {
      const float mf = (bin == p) ? 1.0f : 0.0f;
      acc[p][0] = fmaf(v.x, mf, acc[p][0]);
      acc[p][1] = fmaf(v.y, mf, acc[p][1]);
      acc[p][2] = fmaf(v.z, mf, acc[p][2]);
      acc[p][3] = fmaf(v.w, mf, acc[p][3]);
    }
  }
  // reduce the 4 row-subgroups (lanes stride 16) within the wave
  #pragma unroll
  for (int p = 0; p < kP; ++p) {
    #pragma unroll
    for (int j = 0; j < 4; ++j) {
      float x = acc[p][j];
      x += __shfl_xor(x, 16, 64);
      x += __shfl_xor(x, 32, 64);
      acc[p][j] = x;
    }
  }
  if (lane < 16) {
    #pragma unroll
    for (int p = 0; p < kP; ++p)
      s_res[wv][p][dq] = make_float4(acc[p][0], acc[p][1], acc[p][2], acc[p][3]);
  }
  __syncthreads();                              // single barrier, at the very end

  // epilogue: 256 float4 = 1024 floats per b, fully coalesced
  const int p = tid >> 5, q = tid & 31;
  const float nf = wcnt[b * kP + p] + 1e-4f;    // broadcast load
  float* ob = out + (size_t)b * (kP * 2 * kD) + p * (2 * kD);
  if (q < 16) {                                 // resonance_circle half
    const float4 a = s_res[0][p][q], c = s_res[1][p][q];
    const float4 d2 = s_res[2][p][q], e = s_res[3][p][q];
    float4 o;
    o.x = (a.x + c.x + d2.x + e.x) / nf;
    o.y = (a.y + c.y + d2.y + e.y) / nf;
    o.z = (a.z + c.z + d2.z + e.z) / nf;
    o.w = (a.w + c.w + d2.w + e.w) / nf;
    reinterpret_cast<float4*>(ob)[q] = o;
  } else {                                      // f_scan: relu(s0*W0+s1*W1+b)
    const int d = (q - 16) * 4;
    const float s0 = wdist[b * kP + p] / nf;
    const float s1 = wdir [b * kP + p] / nf;
    float4 o;
    o.x = fmaxf(s0 * Wce[d + 0] + s1 * Wce[kD + d + 0] + bce[d + 0], 0.0f);
    o.y = fmaxf(s0 * Wce[d + 1] + s1 * Wce[kD + d + 1] + bce[d + 1], 0.0f);
    o.z = fmaxf(s0 * Wce[d + 2] + s1 * Wce[kD + d + 2] + bce[d + 2], 0.0f);
    o.w = fmaxf(s0 * Wce[d + 3] + s1 * Wce[kD + d + 3] + bce[d + 3], 0.0f);
    reinterpret_cast<float4*>(ob + kD)[q - 16] = o;
  }
}

extern "C" void kernel_launch(void* const* d_in, const int* in_sizes, int n_in,
                              void* d_out, int out_size, void* d_ws, size_t ws_size,
                              hipStream_t stream) {
  const float* ego  = (const float*)d_in[0];
  const float* nei  = (const float*)d_in[1];
  const float* fres = (const float*)d_in[2];
  const float* Wce  = (const float*)d_in[3];
  const float* bce  = (const float*)d_in[4];
  float* out = (float*)d_out;

  // workspace carve: bins (2 MB) + cnt/dist/dir (3 x 128 KB) = 2.47 MB
  int*   wbin  = (int*)d_ws;
  float* wcnt  = (float*)((char*)d_ws + (size_t)kB * kN * sizeof(int));
  float* wdist = wcnt  + kB * kP;
  float* wdir  = wdist + kB * kP;

  hipLaunchKernelGGL(bin_kernel, dim3(kB), dim3(256), 0, stream,
                     ego, nei, wbin, wcnt, wdist, wdir);
  hipLaunchKernelGGL(gather_kernel, dim3(kB), dim3(256), 0, stream,
                     fres, wbin, wcnt, wdist, wdir, Wce, bce, out);
}